// Round 18
// baseline (84.759 us; speedup 1.0000x reference)
//
#include <hip/hip_runtime.h>
#include <math.h>

#define IMGSZ 256
#define HW (IMGSZ * IMGSZ)
#define EPSF 1e-8f
#define BIGF 1e10f
#define SLICE_LEN 1024
#define MARG 1e-4f
#define CAP 8192         // per-tile bin capacity (packed entries)
#define SEGLEN 128       // max faces per work item
#define RBLOCKS 2048     // raster blocks (256 thr; 4 subtile waves each)
#define QSTEP (2.0f / 262144.0f)   // 18-bit quantization of zlo over [0,2)
// sentinel: all-ones (memset-able); any packed (zbits<<32)|fid is smaller
#define SENTINEL 0xFFFFFFFFFFFFFFFFull

__device__ __forceinline__ float decode_bestz(unsigned long long pk) {
    unsigned hi = (unsigned)(pk >> 32);
    return (hi == 0xFFFFFFFFu) ? BIGF : __uint_as_float(hi);
}

// ---------------- Kernel B: fused vertex-transform + face setup -------------
// Each face transforms its own 3 vertices with the exact expression sequence
// the old k_transform used -> bit-identical xn/yn/z values.
__global__ void k_facesetup(const int* __restrict__ faces,
                            const float* __restrict__ verts,
                            const float* __restrict__ tm,
                            const float* __restrict__ focal,
                            float4* __restrict__ fd,
                            float* __restrict__ vnacc, int F) {
#pragma clang fp contract(off)
    int f = blockIdx.x * blockDim.x + threadIdx.x;
    if (f >= F) return;
    int i0 = faces[f * 3 + 0], i1 = faces[f * 3 + 1], i2 = faces[f * 3 + 2];
    float fx = 2.0f * focal[0] / (float)IMGSZ;
    float fy = 2.0f * focal[1] / (float)IMGSZ;
    float xs[3], ys[3], zs[3];
    int idx[3] = {i0, i1, i2};
#pragma unroll
    for (int k = 0; k < 3; ++k) {
        int i = idx[k];
        float vx = verts[i * 3 + 0], vy = verts[i * 3 + 1], vz = verts[i * 3 + 2];
        float xv = ((vx * tm[0] + vy * tm[4]) + vz * tm[8]) + tm[3];
        float yv = ((vx * tm[1] + vy * tm[5]) + vz * tm[9]) + tm[7];
        float zw = ((vx * tm[2] + vy * tm[6]) + vz * tm[10]) + tm[11];
        float zc = fmaxf(zw, EPSF);
        xs[k] = fx * xv / zc;
        ys[k] = fy * yv / zc;
        zs[k] = zw;
    }
    float x0 = xs[0], x1 = xs[1], x2 = xs[2];
    float y0 = ys[0], y1 = ys[1], y2 = ys[2];
    float z0 = zs[0], z1 = zs[1], z2 = zs[2];
    float area = (x1 - x0) * (y2 - y0) - (x2 - x0) * (y1 - y0);
    bool zok = (z0 > EPSF) && (z1 > EPSF) && (z2 > EPSF);
    float areaStore = zok ? area : 0.0f;  // area==0 => culled (|area|<=EPS)
    float z0c = fmaxf(z0, EPSF), z1c = fmaxf(z1, EPSF), z2c = fmaxf(z2, EPSF);
    float zminb = fminf(fminf(z0c, z1c), z2c) * (1.0f - 1e-5f);
    fd[f * 3 + 0] = make_float4(x0, y0, x1, y1);
    fd[f * 3 + 1] = make_float4(x2, y2, areaStore, __int_as_float(f));
    fd[f * 3 + 2] = make_float4(z0c, z1c, z2c, zminb);
    float a0 = verts[i0 * 3 + 0], a1 = verts[i0 * 3 + 1], a2 = verts[i0 * 3 + 2];
    float b0 = verts[i1 * 3 + 0], b1 = verts[i1 * 3 + 1], b2 = verts[i1 * 3 + 2];
    float c0 = verts[i2 * 3 + 0], c1 = verts[i2 * 3 + 1], c2 = verts[i2 * 3 + 2];
    float e1x = b0 - a0, e1y = b1 - a1, e1z = b2 - a2;
    float e2x = c0 - a0, e2y = c1 - a1, e2z = c2 - a2;
    float nx = e1y * e2z - e1z * e2y;
    float ny = e1z * e2x - e1x * e2z;
    float nz = e1x * e2y - e1y * e2x;
    atomicAdd(&vnacc[i0 * 3 + 0], nx);
    atomicAdd(&vnacc[i0 * 3 + 1], ny);
    atomicAdd(&vnacc[i0 * 3 + 2], nz);
    atomicAdd(&vnacc[i1 * 3 + 0], nx);
    atomicAdd(&vnacc[i1 * 3 + 1], ny);
    atomicAdd(&vnacc[i1 * 3 + 2], nz);
    atomicAdd(&vnacc[i2 * 3 + 0], nx);
    atomicAdd(&vnacc[i2 * 3 + 1], ny);
    atomicAdd(&vnacc[i2 * 3 + 2], nz);
}

// helper: tile NDC bounds (identical expressions everywhere)
__device__ __forceinline__ void tile_bounds(int tileX, int tileY,
                                            float& txmin, float& txmax,
                                            float& tymin, float& tymax) {
#pragma clang fp contract(off)
    txmax = 1.0f - 2.0f * ((float)(tileX * 16) + 0.5f) / (float)IMGSZ;
    txmin = 1.0f - 2.0f * ((float)(tileX * 16 + 15) + 0.5f) / (float)IMGSZ;
    tymax = 1.0f - 2.0f * ((float)(tileY * 16) + 0.5f) / (float)IMGSZ;
    tymin = 1.0f - 2.0f * ((float)(tileY * 16 + 15) + 0.5f) / (float)IMGSZ;
}

// conservative rect-vs-triangle test (same construction as tile cull)
__device__ __forceinline__ bool rect_cull(float x0, float y0, float x1, float y1,
                                          float x2, float y2, float area,
                                          float rxmin, float rxmax,
                                          float rymin, float rymax) {
#pragma clang fp contract(off)
    const float M = 1e-4f;
    float mnx = fminf(fminf(x0, x1), x2);
    float mxx = fmaxf(fmaxf(x0, x1), x2);
    float mny = fminf(fminf(y0, y1), y2);
    float mxy = fmaxf(fmaxf(y0, y1), y2);
    bool pass = (mnx <= rxmax + M) && (mxx >= rxmin - M) &&
                (mny <= rymax + M) && (mxy >= rymin - M);
    if (!pass) return false;
    float a0 = y1 - y2, bb0 = x2 - x1, k0 = x1 * y2 - x2 * y1;
    float a1 = y2 - y0, bb1 = x0 - x2, k1 = x2 * y0 - x0 * y2;
    float a2 = y0 - y1, bb2 = x1 - x0, k2 = x0 * y1 - x1 * y0;
    if (area > 0.0f) {
        float w0m = k0 + fmaxf(a0 * rxmin, a0 * rxmax) + fmaxf(bb0 * rymin, bb0 * rymax);
        float w1m = k1 + fmaxf(a1 * rxmin, a1 * rxmax) + fmaxf(bb1 * rymin, bb1 * rymax);
        float w2m = k2 + fmaxf(a2 * rxmin, a2 * rxmax) + fmaxf(bb2 * rymin, bb2 * rymax);
        return (w0m >= -MARG) && (w1m >= -MARG) && (w2m >= -MARG);
    } else {
        float w0m = k0 + fminf(a0 * rxmin, a0 * rxmax) + fminf(bb0 * rymin, bb0 * rymax);
        float w1m = k1 + fminf(a1 * rxmin, a1 * rxmax) + fminf(bb1 * rymin, bb1 * rymax);
        float w2m = k2 + fminf(a2 * rxmin, a2 * rxmax) + fminf(bb2 * rymin, bb2 * rymax);
        return (w0m <= MARG) && (w1m <= MARG) && (w2m <= MARG);
    }
}

// ---------------- Kernel F: tile-major cull + bin (packed zlo|fid) ----------
__launch_bounds__(256)
__global__ void k_bincull(const float4* __restrict__ fd, int F,
                          int* __restrict__ cnt, unsigned* __restrict__ bins,
                          unsigned long long* __restrict__ zb) {
#pragma clang fp contract(off)
    __shared__ int scnt[4];
    __shared__ int sbase;
    int t = threadIdx.x;
    int lane = t & 63, wid = t >> 6;
    int tile = blockIdx.x >> 2;
    int q = blockIdx.x & 3;
    int tileX = tile & 15, tileY = tile >> 4;
    float txmin, txmax, tymin, tymax;
    tile_bounds(tileX, tileY, txmin, txmax, tymin, tymax);
    int Fq = (F + 3) >> 2;
    int fbeg = q * Fq;
    int fend = min(F, fbeg + Fq);
    int binbase = tile * CAP;

    for (int base = fbeg; base < fend; base += 256) {
        int f = base + t;
        bool pass = false;
        unsigned entry = 0;
        float x0, y0, x1, y1, x2, y2, area;
        float4 Bv;
        if (f < fend) {
            float4 A = fd[f * 3 + 0];
            Bv = fd[f * 3 + 1];
            area = Bv.z;
            if (fabsf(area) > EPSF) {
                x0 = A.x; y0 = A.y; x1 = A.z; y1 = A.w; x2 = Bv.x; y2 = Bv.y;
                pass = rect_cull(x0, y0, x1, y1, x2, y2, area,
                                 txmin, txmax, tymin, tymax);
                if (pass) {
                    // per-(tile,face) conservative depth lower bound:
                    // invz affine in (P,Q) -> max at tile corner; zlo = 1/max
                    float4 Cv = fd[f * 3 + 2];
                    float r0 = 1.0f / (area * Cv.x);
                    float r1 = 1.0f / (area * Cv.y);
                    float r2 = 1.0f / (area * Cv.z);
                    float a0 = y1 - y2, bb0 = x2 - x1, k0 = x1 * y2 - x2 * y1;
                    float a1 = y2 - y0, bb1 = x0 - x2, k1 = x2 * y0 - x0 * y2;
                    float a2 = y0 - y1, bb2 = x1 - x0, k2 = x0 * y1 - x1 * y0;
                    float K = (k0 * r0 + k1 * r1) + k2 * r2;
                    float GX = (a0 * r0 + a1 * r1) + a2 * r2;
                    float GY = (bb0 * r0 + bb1 * r1) + bb2 * r2;
                    float gx = fmaxf(GX * txmin, GX * txmax);
                    float gy = fmaxf(GY * tymin, GY * tymax);
                    float invmax = K + gx + gy;
                    float mag = (fabsf(k0 * r0) + fabsf(k1 * r1) + fabsf(k2 * r2))
                              + fmaxf(fabsf(GX * txmin), fabsf(GX * txmax))
                              + fmaxf(fabsf(GY * tymin), fabsf(GY * tymax));
                    invmax = invmax + 1e-5f * mag;
                    float zlo = (1.0f / fmaxf(invmax, EPSF)) * (1.0f - 1e-5f);
                    float qf = zlo * (1.0f / QSTEP);
                    int qz = (int)qf;             // floor for qf>=0
                    if (qf < 0.0f) qz = 0;
                    if (qz > 262143) qz = 262143;
                    entry = ((unsigned)qz << 14) | (unsigned)f;
                }
            }
        }
        unsigned long long m = __ballot(pass);
        if (lane == 0) scnt[wid] = __popcll(m);
        __syncthreads();
        int off = 0;
#pragma unroll
        for (int w = 0; w < 4; ++w)
            if (w < wid) off += scnt[w];
        int total = scnt[0] + scnt[1] + scnt[2] + scnt[3];
        if (t == 0) sbase = (total > 0) ? atomicAdd(&cnt[tile], total) : 0;
        __syncthreads();
        int sb = sbase;
        if (pass) {
            int rank = __popcll(m & ((1ull << lane) - 1ull));
            int s = sb + off + rank;
            if (s < CAP) {
                bins[binbase + s] = entry;
            } else {
                // overflow safety net (normally dead): rasterize directly
                float4 c = fd[f * 3 + 2];
                for (int p = 0; p < 256; ++p) {
                    int colp = tileX * 16 + (p & 15), rowp = tileY * 16 + (p >> 4);
                    float P = 1.0f - 2.0f * ((float)colp + 0.5f) / (float)IMGSZ;
                    float Q = 1.0f - 2.0f * ((float)rowp + 0.5f) / (float)IMGSZ;
                    float e0x = x0 - P, e0y = y0 - Q;
                    float e1x = x1 - P, e1y = y1 - Q;
                    float e2x = x2 - P, e2y = y2 - Q;
                    float w0 = e1x * e2y - e2x * e1y;
                    float w1 = e2x * e0y - e0x * e2y;
                    float w2 = (area - w0) - w1;
                    bool inside = (area > 0.0f) ? (w0 >= 0.0f && w1 >= 0.0f && w2 >= 0.0f)
                                                : (w0 <= 0.0f && w1 <= 0.0f && w2 <= 0.0f);
                    if (inside) {
                        float b0v = w0 / area, b1v = w1 / area, b2v = w2 / area;
                        float t0 = b0v / c.x, t1 = b1v / c.y, t2v = b2v / c.z;
                        float invz = (t0 + t1) + t2v;
                        float zpix = 1.0f / fmaxf(invz, EPSF);
                        unsigned long long pk =
                            ((unsigned long long)(unsigned int)__float_as_int(zpix) << 32) |
                            (unsigned int)__float_as_int(Bv.w);
                        atomicMin(&zb[rowp * IMGSZ + colp], pk);
                    }
                }
            }
        }
        __syncthreads();
    }
}

// ---------------- Kernel S: per-tile counting sort + fused work-list --------
__launch_bounds__(256)
__global__ void k_binsort(const int* __restrict__ cnt,
                          unsigned* __restrict__ bins,
                          unsigned short* __restrict__ workl,
                          int* __restrict__ worktotal) {
    __shared__ unsigned sent[CAP];       // 32 KB
    __shared__ int hist[64], hbase[64];
    __shared__ int sn[256], snseg[256], sord[256], spre[256];
    int t = threadIdx.x;
    if (blockIdx.x == 256) {
        int n = cnt[t];
        if (n > CAP) n = CAP;
        int ns = (n > 0) ? (n + SEGLEN - 1) / SEGLEN : 0;
        sn[t] = n;
        snseg[t] = ns;
        __syncthreads();
        int r = 0;
        for (int k = 0; k < 256; ++k) {
            int nk = sn[k];
            r += (nk > n) || (nk == n && k < t);
        }
        sord[r] = t;
        __syncthreads();
        if (t == 0) {
            int run = 0;
            for (int k = 0; k < 256; ++k) { spre[k] = run; run += snseg[sord[k]]; }
            *worktotal = run;
        }
        __syncthreads();
        int tile = sord[t];
        int base = spre[t];
        int ns2 = snseg[tile];
        for (int seg = 0; seg < ns2; ++seg)
            workl[base + seg] = (unsigned short)((tile << 6) | seg);
        return;
    }
    int tile = blockIdx.x;
    int n = cnt[tile];
    if (n > CAP) n = CAP;
    if (n == 0) return;
    int nseg = (n + SEGLEN - 1) / SEGLEN;
    if (t < 64) hist[t] = 0;
    __syncthreads();
    for (int i = t; i < n; i += 256) {
        unsigned e = bins[tile * CAP + i];
        sent[i] = e;
        atomicAdd(&hist[e >> 26], 1);
    }
    __syncthreads();
    if (t == 0) {
        int run = 0;
        for (int k = 0; k < 64; ++k) { hbase[k] = run; run += hist[k]; }
    }
    __syncthreads();
    if (t < 64) hist[t] = 0;   // reuse as per-bucket fill counter
    __syncthreads();
    for (int i = t; i < n; i += 256) {
        unsigned e = sent[i];
        int b = e >> 26;
        int pos = hbase[b] + atomicAdd(&hist[b], 1);
        int tpos = (pos % nseg) * SEGLEN + pos / nseg;
        bins[tile * CAP + tpos] = e;
    }
}

// ---------------- Kernel D: (tile,seg) blocks; shared staging; subtile waves
__launch_bounds__(256)
__global__ void k_rastseg(const float4* __restrict__ fd,
                          const int* __restrict__ cnt,
                          const unsigned* __restrict__ bins,
                          const unsigned short* __restrict__ workl,
                          const int* __restrict__ worktotal,
                          unsigned long long* __restrict__ zb) {
#pragma clang fp contract(off)
    __shared__ float4 sA[64], sB[64], sC[64];
    __shared__ unsigned sE[64];
    __shared__ int sdone[4];
    int total = *worktotal;
    int wave = threadIdx.x >> 6;
    int lane = threadIdx.x & 63;
    int t = threadIdx.x;
    for (int wi = blockIdx.x; wi < total; wi += gridDim.x) {
        int w = workl[wi];
        int tile = w >> 6, seg = w & 63;
        int n = cnt[tile];
        if (n > CAP) n = CAP;
        int nseg = (n + SEGLEN - 1) / SEGLEN;
        int nb = (n - 1 - seg) / nseg + 1;   // subsequence length (<= SEGLEN)
        int binbase = tile * CAP + seg * SEGLEN;

        int tileX = tile & 15, tileY = tile >> 4;
        int col0 = tileX * 16 + ((wave & 1) << 3);
        int row0 = tileY * 16 + ((wave >> 1) << 3);
        int col = col0 + (lane & 7);
        int row = row0 + (lane >> 3);
        int pix = row * IMGSZ + col;
        float P = 1.0f - 2.0f * ((float)col + 0.5f) / (float)IMGSZ;
        float Q = 1.0f - 2.0f * ((float)row + 0.5f) / (float)IMGSZ;
        float sxmax = 1.0f - 2.0f * ((float)col0 + 0.5f) / (float)IMGSZ;
        float sxmin = 1.0f - 2.0f * ((float)(col0 + 7) + 0.5f) / (float)IMGSZ;
        float symax = 1.0f - 2.0f * ((float)row0 + 0.5f) / (float)IMGSZ;
        float symin = 1.0f - 2.0f * ((float)(row0 + 7) + 0.5f) / (float)IMGSZ;

        unsigned long long seed = zb[pix];
        unsigned long long bestpk = seed;
        float bestz = decode_bestz(seed);
        bool done = false;
        if (lane == 0) sdone[wave] = 0;

        for (int k0 = 0; k0 < nb; k0 += 64) {
            int cnum = min(64, nb - k0);
            __syncthreads();  // LDS reuse + sdone visibility
            if (sdone[0] + sdone[1] + sdone[2] + sdone[3] == 4) break;
            if (t < 192) {
                int part = t >> 6, fi = t & 63;
                if (fi < cnum) {
                    unsigned e = bins[binbase + k0 + fi];
                    int fid = e & 0x3FFF;
                    if (part == 0) { sE[fi] = e; sA[fi] = fd[fid * 3 + 0]; }
                    else if (part == 1) sB[fi] = fd[fid * 3 + 1];
                    else sC[fi] = fd[fid * 3 + 2];
                }
            }
            __syncthreads();
            if (!done) {
                bool pass8 = false;
                if (lane < cnum) {
                    float4 ra = sA[lane], rb = sB[lane];
                    float area = rb.z;
                    if (fabsf(area) > EPSF)
                        pass8 = rect_cull(ra.x, ra.y, ra.z, ra.w, rb.x, rb.y,
                                          area, sxmin, sxmax, symin, symax);
                }
                unsigned long long mm = __ballot(pass8);
                int it = 0;
                while (mm) {
                    int s = __ffsll(mm) - 1;
                    mm &= mm - 1;
                    unsigned e = sE[s];
                    float zlo = (float)(e >> 14) * QSTEP;
                    if ((it++ & 7) == 0) {
                        // subsequence ascending in bucket(e>>26): remaining
                        // faces' zpix >= bucket-lo; if > all bestz, every
                        // remaining pk is strictly worse. Bit-exact.
                        float blo = (float)(e >> 26) * (4096.0f * QSTEP);
                        if (__all(blo > bestz)) {
                            done = true;
                            if (lane == 0) sdone[wave] = 1;
                            break;
                        }
                    }
                    if (zlo > bestz) {
                        if (__all(zlo > bestz)) continue;
                    }
                    float4 a = sA[s], b = sB[s];
                    float area = b.z;
                    float e0x = a.x - P, e0y = a.y - Q;
                    float e1x = a.z - P, e1y = a.w - Q;
                    float e2x = b.x - P, e2y = b.y - Q;
                    float w0 = e1x * e2y - e2x * e1y;
                    float w1 = e2x * e0y - e0x * e2y;
                    float w2 = (area - w0) - w1;
                    bool inside = (area > 0.0f) ? (w0 >= 0.0f && w1 >= 0.0f && w2 >= 0.0f)
                                                : (w0 <= 0.0f && w1 <= 0.0f && w2 <= 0.0f);
                    bool want = inside && !(zlo > bestz);
                    if (want) {
                        float4 cc = sC[s];
                        float b0v = w0 / area, b1v = w1 / area, b2v = w2 / area;
                        float t0 = b0v / cc.x, t1 = b1v / cc.y, t2v = b2v / cc.z;
                        float invz = (t0 + t1) + t2v;
                        float zpix = 1.0f / fmaxf(invz, EPSF);
                        unsigned long long pk =
                            ((unsigned long long)(unsigned int)__float_as_int(zpix) << 32) |
                            (unsigned int)__float_as_int(b.w);
                        if (pk < bestpk) {
                            bestpk = pk;
                            bestz = zpix;
                        }
                    }
                }
            }
        }
        if (bestpk < seed) atomicMin(&zb[pix], bestpk);
        __syncthreads();  // all waves finished with this item's LDS
    }
}

// ---------------- Kernel D-mono: fallback (small ws_size) -------------------
__launch_bounds__(256)
__global__ void k_raster_mono(const float4* __restrict__ fd, int F,
                              unsigned long long* __restrict__ zb) {
#pragma clang fp contract(off)
    __shared__ float4 sfd[256 * 3];
    __shared__ int scnt[4];
    int t = threadIdx.x;
    int lane = t & 63, wid = t >> 6;
    int tile = blockIdx.x & 255;
    int slice = blockIdx.x >> 8;
    int tileX = tile & 15, tileY = tile >> 4;
    int col = tileX * 16 + (t & 15);
    int row = tileY * 16 + (t >> 4);
    int pix = row * IMGSZ + col;
    float P = 1.0f - 2.0f * ((float)col + 0.5f) / (float)IMGSZ;
    float Q = 1.0f - 2.0f * ((float)row + 0.5f) / (float)IMGSZ;
    float txmin, txmax, tymin, tymax;
    tile_bounds(tileX, tileY, txmin, txmax, tymin, tymax);
    int fbeg = slice * SLICE_LEN;
    int fend = fbeg + SLICE_LEN;
    if (fend > F) fend = F;
    unsigned long long bestpk = SENTINEL;
    float bestz = BIGF;
    for (int base = fbeg; base < fend; base += 256) {
        unsigned long long ext = zb[pix];
        if (ext < bestpk) {
            bestpk = ext;
            bestz = decode_bestz(ext);
        }
        int f = base + t;
        bool pass = false;
        float4 A, B, C;
        if (f < fend) {
            A = fd[f * 3 + 0];
            B = fd[f * 3 + 1];
            C = fd[f * 3 + 2];
            float area = B.z;
            if (fabsf(area) > EPSF)
                pass = rect_cull(A.x, A.y, A.z, A.w, B.x, B.y, area,
                                 txmin, txmax, tymin, tymax);
        }
        unsigned long long m = __ballot(pass);
        if (lane == 0) scnt[wid] = __popcll(m);
        __syncthreads();
        int off = 0;
#pragma unroll
        for (int w = 0; w < 4; ++w)
            if (w < wid) off += scnt[w];
        int total = scnt[0] + scnt[1] + scnt[2] + scnt[3];
        if (pass) {
            int rank = __popcll(m & ((1ull << lane) - 1ull));
            int s = off + rank;
            sfd[s * 3 + 0] = A;
            sfd[s * 3 + 1] = B;
            sfd[s * 3 + 2] = C;
        }
        __syncthreads();
        for (int s = 0; s < total; ++s) {
            float4 a = sfd[s * 3 + 0], b = sfd[s * 3 + 1], c = sfd[s * 3 + 2];
            float e0x = a.x - P, e0y = a.y - Q;
            float e1x = a.z - P, e1y = a.w - Q;
            float e2x = b.x - P, e2y = b.y - Q;
            float w0 = e1x * e2y - e2x * e1y;
            float w1 = e2x * e0y - e0x * e2y;
            float area = b.z;
            float w2 = (area - w0) - w1;
            bool inside = (area > 0.0f) ? (w0 >= 0.0f && w1 >= 0.0f && w2 >= 0.0f)
                                        : (w0 <= 0.0f && w1 <= 0.0f && w2 <= 0.0f);
            bool want = inside && !(c.w > bestz);  // equality-safe (zminb)
            if (want) {
                float b0v = w0 / area, b1v = w1 / area, b2v = w2 / area;
                float t0 = b0v / c.x, t1 = b1v / c.y, t2v = b2v / c.z;
                float invz = (t0 + t1) + t2v;
                float zpix = 1.0f / fmaxf(invz, EPSF);
                unsigned long long pk =
                    ((unsigned long long)(unsigned int)__float_as_int(zpix) << 32) |
                    (unsigned int)__float_as_int(b.w);
                if (pk < bestpk) {
                    bestpk = pk;
                    bestz = zpix;
                }
            }
        }
        if (bestpk < ext) atomicMin(&zb[pix], bestpk);
        __syncthreads();
    }
}

// ---------------- Kernel E: shade winners (inline normal normalize) ---------
__launch_bounds__(256)
__global__ void k_shade(const unsigned long long* __restrict__ zb,
                        const float4* __restrict__ fd,
                        const int* __restrict__ faces,
                        const float* __restrict__ verts,
                        const float* __restrict__ vn,
                        const float* __restrict__ tm,
                        float* __restrict__ out) {
#pragma clang fp contract(off)
    int pix = blockIdx.x * 256 + threadIdx.x;
    unsigned long long pk = zb[pix];
    float val = 0.0f, alpha = 0.0f;
    if (pk != SENTINEL) {
        float depth = __uint_as_float((unsigned int)(pk >> 32));
        if (depth < 0.5f * BIGF) {
            int bestf = (int)(unsigned int)(pk & 0xFFFFFFFFull);
            int col = pix & (IMGSZ - 1), row = pix >> 8;
            float P = 1.0f - 2.0f * ((float)col + 0.5f) / (float)IMGSZ;
            float Q = 1.0f - 2.0f * ((float)row + 0.5f) / (float)IMGSZ;
            float4 a = fd[bestf * 3 + 0], b = fd[bestf * 3 + 1], c = fd[bestf * 3 + 2];
            float e0x = a.x - P, e0y = a.y - Q;
            float e1x = a.z - P, e1y = a.w - Q;
            float e2x = b.x - P, e2y = b.y - Q;
            float w0 = e1x * e2y - e2x * e1y;
            float w1 = e2x * e0y - e0x * e2y;
            float area = b.z;
            float t0 = (w0 / area) / c.x, t1 = (w1 / area) / c.y;
            float t2v = (((area - w0) - w1) / area) / c.z;
            float invz = (t0 + t1) + t2v;
            float zpix = 1.0f / fmaxf(invz, EPSF);
            float bp0 = t0 * zpix, bp1 = t1 * zpix;

            int i0 = faces[bestf * 3 + 0], i1 = faces[bestf * 3 + 1], i2 = faces[bestf * 3 + 2];
            float b0v = bp0, b1v = bp1, b2v = (1.0f - bp0) - bp1;
            float Pwx = (b0v * verts[i0 * 3 + 0] + b1v * verts[i1 * 3 + 0]) + b2v * verts[i2 * 3 + 0];
            float Pwy = (b0v * verts[i0 * 3 + 1] + b1v * verts[i1 * 3 + 1]) + b2v * verts[i2 * 3 + 1];
            float Pwz = (b0v * verts[i0 * 3 + 2] + b1v * verts[i1 * 3 + 2]) + b2v * verts[i2 * 3 + 2];
            float v0x = vn[i0 * 3 + 0], v0y = vn[i0 * 3 + 1], v0z = vn[i0 * 3 + 2];
            float n0 = sqrtf((v0x * v0x + v0y * v0y) + v0z * v0z) + EPSF;
            v0x /= n0; v0y /= n0; v0z /= n0;
            float v1x = vn[i1 * 3 + 0], v1y = vn[i1 * 3 + 1], v1z = vn[i1 * 3 + 2];
            float n1 = sqrtf((v1x * v1x + v1y * v1y) + v1z * v1z) + EPSF;
            v1x /= n1; v1y /= n1; v1z /= n1;
            float v2x = vn[i2 * 3 + 0], v2y = vn[i2 * 3 + 1], v2z = vn[i2 * 3 + 2];
            float n2 = sqrtf((v2x * v2x + v2y * v2y) + v2z * v2z) + EPSF;
            v2x /= n2; v2y /= n2; v2z /= n2;
            float Nx = (b0v * v0x + b1v * v1x) + b2v * v2x;
            float Ny = (b0v * v0y + b1v * v1y) + b2v * v2y;
            float Nz = (b0v * v0z + b1v * v1z) + b2v * v2z;
            float nn = sqrtf((Nx * Nx + Ny * Ny) + Nz * Nz) + EPSF;
            Nx /= nn; Ny /= nn; Nz /= nn;
            float T0 = tm[3], T1 = tm[7], T2 = tm[11];
            float camx = -((T0 * tm[0] + T1 * tm[1]) + T2 * tm[2]);
            float camy = -((T0 * tm[4] + T1 * tm[5]) + T2 * tm[6]);
            float camz = -((T0 * tm[8] + T1 * tm[9]) + T2 * tm[10]);
            float Ldx = 0.0f - Pwx, Ldy = 0.0f - Pwy, Ldz = 3.0f - Pwz;
            float ln = sqrtf((Ldx * Ldx + Ldy * Ldy) + Ldz * Ldz) + EPSF;
            Ldx /= ln; Ldy /= ln; Ldz /= ln;
            float Vx = camx - Pwx, Vy = camy - Pwy, Vz = camz - Pwz;
            float vv = sqrtf((Vx * Vx + Vy * Vy) + Vz * Vz) + EPSF;
            Vx /= vv; Vy /= vv; Vz /= vv;
            float dt = (Nx * Ldx + Ny * Ldy) + Nz * Ldz;
            float ndl = fmaxf(dt, 0.0f);
            float twodt = 2.0f * dt;
            float rx = -Ldx + twodt * Nx;
            float ry = -Ldy + twodt * Ny;
            float rz = -Ldz + twodt * Nz;
            float sdot = (rx * Vx + ry * Vy) + rz * Vz;
            float sb = fmaxf(sdot, 0.0f);
            float s2 = sb * sb, s4 = s2 * s2, s8 = s4 * s4, s16 = s8 * s8, s32 = s16 * s16;
            float spec = s32 * s32;  // sb^64
            float shade = (0.5f + 0.3f * ndl) + 0.2f * spec;
            val = shade * 255.0f;
            alpha = 1.0f;
        }
    }
    out[0 * HW + pix] = val;
    out[1 * HW + pix] = val;
    out[2 * HW + pix] = val;
    out[3 * HW + pix] = alpha;
}

// ---------------- launcher --------------------------------------------------
extern "C" void kernel_launch(void* const* d_in, const int* in_sizes, int n_in,
                              void* d_out, int out_size, void* d_ws, size_t ws_size,
                              hipStream_t stream) {
    const float* verts = (const float*)d_in[0];
    const float* tm = (const float*)d_in[1];
    const float* focal = (const float*)d_in[2];
    const int* faces = (const int*)d_in[3];
    int V = in_sizes[0] / 3;  // B=1
    int F = in_sizes[3] / 3;

    char* base = (char*)d_ws;
    unsigned long long* zb = (unsigned long long*)base;            // HW*8
    int* cnt = (int*)(base + (size_t)HW * 8);                      // 4KB
    float* vn = (float*)(base + (size_t)HW * 8 + 4096);            // 3V floats
    size_t fdByte = ((size_t)HW * 8 + 4096 + 3 * (size_t)V * 4 + 15) & ~(size_t)15;
    float4* fd = (float4*)(base + fdByte);
    size_t binByte = fdByte + (size_t)F * 48;
    unsigned* bins = (unsigned*)(base + binByte);
    size_t workByte = binByte + (size_t)256 * CAP * 4;
    unsigned short* workl = (unsigned short*)(base + workByte);    // <=16384 u16
    int* worktotal = (int*)(base + workByte + 16384 * 2);
    size_t needBinned = workByte + 16384 * 2 + 64;
    float* out = (float*)d_out;

    int fb = (F + 255) / 256;
    // async init: zb sentinel = all-ones; cnt+vn zeros (adjacent region)
    hipMemsetAsync(zb, 0xFF, (size_t)HW * 8, stream);
    hipMemsetAsync(cnt, 0, 4096 + 3 * (size_t)V * 4, stream);
    k_facesetup<<<fb, 256, 0, stream>>>(faces, verts, tm, focal, fd, vn, F);
    if (ws_size >= needBinned) {
        k_bincull<<<256 * 4, 256, 0, stream>>>(fd, F, cnt, bins, zb);
        k_binsort<<<257, 256, 0, stream>>>(cnt, bins, workl, worktotal);
        k_rastseg<<<RBLOCKS, 256, 0, stream>>>(fd, cnt, bins, workl, worktotal, zb);
    } else {
        int nslice = (F + SLICE_LEN - 1) / SLICE_LEN;
        k_raster_mono<<<256 * nslice, 256, 0, stream>>>(fd, F, zb);
    }
    k_shade<<<HW / 256, 256, 0, stream>>>(zb, fd, faces, verts, vn, tm, out);
}

// Round 19
// 79.907 us; speedup vs baseline: 1.0607x; 1.0607x over previous
//
#include <hip/hip_runtime.h>
#include <math.h>

#define IMGSZ 256
#define HW (IMGSZ * IMGSZ)
#define EPSF 1e-8f
#define BIGF 1e10f
#define SLICE_LEN 1024
#define MARG 1e-4f
#define CAP 8192         // per-tile bin capacity (packed entries)
#define SEGLEN 128       // max faces per work item
#define RBLOCKS 2048     // raster blocks (256 thr; 4 subtile waves each)
#define QSTEP (2.0f / 262144.0f)   // 18-bit quantization of zlo over [0,2)
// sentinel: all-ones; any packed (zbits<<32)|fid is smaller
#define SENTINEL 0xFFFFFFFFFFFFFFFFull

__device__ __forceinline__ float decode_bestz(unsigned long long pk) {
    unsigned hi = (unsigned)(pk >> 32);
    return (hi == 0xFFFFFFFFu) ? BIGF : __uint_as_float(hi);
}

// ---------------- Kernel I: init zb sentinel + cnt/vnacc zeros --------------
__global__ void k_init(unsigned long long* __restrict__ zb,
                       int* __restrict__ cnt, float* __restrict__ vnacc,
                       int V) {
    int i = blockIdx.x * blockDim.x + threadIdx.x;
    int nth = gridDim.x * blockDim.x;
    for (int j = i; j < HW; j += nth) zb[j] = SENTINEL;
    if (i < 256) cnt[i] = 0;
    for (int j = i; j < 3 * V; j += nth) vnacc[j] = 0.0f;
}

// ---------------- Kernel B: fused vertex-transform + face setup -------------
// Each face transforms its own 3 vertices with the exact expression sequence
// the original k_transform used -> bit-identical xn/yn/z values.
__global__ void k_facesetup(const int* __restrict__ faces,
                            const float* __restrict__ verts,
                            const float* __restrict__ tm,
                            const float* __restrict__ focal,
                            float4* __restrict__ fd,
                            float* __restrict__ vnacc, int F) {
#pragma clang fp contract(off)
    int f = blockIdx.x * blockDim.x + threadIdx.x;
    if (f >= F) return;
    int i0 = faces[f * 3 + 0], i1 = faces[f * 3 + 1], i2 = faces[f * 3 + 2];
    float fx = 2.0f * focal[0] / (float)IMGSZ;
    float fy = 2.0f * focal[1] / (float)IMGSZ;
    float xs[3], ys[3], zs[3];
    int idx[3] = {i0, i1, i2};
#pragma unroll
    for (int k = 0; k < 3; ++k) {
        int i = idx[k];
        float vx = verts[i * 3 + 0], vy = verts[i * 3 + 1], vz = verts[i * 3 + 2];
        float xv = ((vx * tm[0] + vy * tm[4]) + vz * tm[8]) + tm[3];
        float yv = ((vx * tm[1] + vy * tm[5]) + vz * tm[9]) + tm[7];
        float zw = ((vx * tm[2] + vy * tm[6]) + vz * tm[10]) + tm[11];
        float zc = fmaxf(zw, EPSF);
        xs[k] = fx * xv / zc;
        ys[k] = fy * yv / zc;
        zs[k] = zw;
    }
    float x0 = xs[0], x1 = xs[1], x2 = xs[2];
    float y0 = ys[0], y1 = ys[1], y2 = ys[2];
    float z0 = zs[0], z1 = zs[1], z2 = zs[2];
    float area = (x1 - x0) * (y2 - y0) - (x2 - x0) * (y1 - y0);
    bool zok = (z0 > EPSF) && (z1 > EPSF) && (z2 > EPSF);
    float areaStore = zok ? area : 0.0f;  // area==0 => culled (|area|<=EPS)
    float z0c = fmaxf(z0, EPSF), z1c = fmaxf(z1, EPSF), z2c = fmaxf(z2, EPSF);
    float zminb = fminf(fminf(z0c, z1c), z2c) * (1.0f - 1e-5f);
    fd[f * 3 + 0] = make_float4(x0, y0, x1, y1);
    fd[f * 3 + 1] = make_float4(x2, y2, areaStore, __int_as_float(f));
    fd[f * 3 + 2] = make_float4(z0c, z1c, z2c, zminb);
    float a0 = verts[i0 * 3 + 0], a1 = verts[i0 * 3 + 1], a2 = verts[i0 * 3 + 2];
    float b0 = verts[i1 * 3 + 0], b1 = verts[i1 * 3 + 1], b2 = verts[i1 * 3 + 2];
    float c0 = verts[i2 * 3 + 0], c1 = verts[i2 * 3 + 1], c2 = verts[i2 * 3 + 2];
    float e1x = b0 - a0, e1y = b1 - a1, e1z = b2 - a2;
    float e2x = c0 - a0, e2y = c1 - a1, e2z = c2 - a2;
    float nx = e1y * e2z - e1z * e2y;
    float ny = e1z * e2x - e1x * e2z;
    float nz = e1x * e2y - e1y * e2x;
    atomicAdd(&vnacc[i0 * 3 + 0], nx);
    atomicAdd(&vnacc[i0 * 3 + 1], ny);
    atomicAdd(&vnacc[i0 * 3 + 2], nz);
    atomicAdd(&vnacc[i1 * 3 + 0], nx);
    atomicAdd(&vnacc[i1 * 3 + 1], ny);
    atomicAdd(&vnacc[i1 * 3 + 2], nz);
    atomicAdd(&vnacc[i2 * 3 + 0], nx);
    atomicAdd(&vnacc[i2 * 3 + 1], ny);
    atomicAdd(&vnacc[i2 * 3 + 2], nz);
}

// helper: tile NDC bounds (identical expressions everywhere)
__device__ __forceinline__ void tile_bounds(int tileX, int tileY,
                                            float& txmin, float& txmax,
                                            float& tymin, float& tymax) {
#pragma clang fp contract(off)
    txmax = 1.0f - 2.0f * ((float)(tileX * 16) + 0.5f) / (float)IMGSZ;
    txmin = 1.0f - 2.0f * ((float)(tileX * 16 + 15) + 0.5f) / (float)IMGSZ;
    tymax = 1.0f - 2.0f * ((float)(tileY * 16) + 0.5f) / (float)IMGSZ;
    tymin = 1.0f - 2.0f * ((float)(tileY * 16 + 15) + 0.5f) / (float)IMGSZ;
}

// conservative rect-vs-triangle test (same construction as tile cull)
__device__ __forceinline__ bool rect_cull(float x0, float y0, float x1, float y1,
                                          float x2, float y2, float area,
                                          float rxmin, float rxmax,
                                          float rymin, float rymax) {
#pragma clang fp contract(off)
    const float M = 1e-4f;
    float mnx = fminf(fminf(x0, x1), x2);
    float mxx = fmaxf(fmaxf(x0, x1), x2);
    float mny = fminf(fminf(y0, y1), y2);
    float mxy = fmaxf(fmaxf(y0, y1), y2);
    bool pass = (mnx <= rxmax + M) && (mxx >= rxmin - M) &&
                (mny <= rymax + M) && (mxy >= rymin - M);
    if (!pass) return false;
    float a0 = y1 - y2, bb0 = x2 - x1, k0 = x1 * y2 - x2 * y1;
    float a1 = y2 - y0, bb1 = x0 - x2, k1 = x2 * y0 - x0 * y2;
    float a2 = y0 - y1, bb2 = x1 - x0, k2 = x0 * y1 - x1 * y0;
    if (area > 0.0f) {
        float w0m = k0 + fmaxf(a0 * rxmin, a0 * rxmax) + fmaxf(bb0 * rymin, bb0 * rymax);
        float w1m = k1 + fmaxf(a1 * rxmin, a1 * rxmax) + fmaxf(bb1 * rymin, bb1 * rymax);
        float w2m = k2 + fmaxf(a2 * rxmin, a2 * rxmax) + fmaxf(bb2 * rymin, bb2 * rymax);
        return (w0m >= -MARG) && (w1m >= -MARG) && (w2m >= -MARG);
    } else {
        float w0m = k0 + fminf(a0 * rxmin, a0 * rxmax) + fminf(bb0 * rymin, bb0 * rymax);
        float w1m = k1 + fminf(a1 * rxmin, a1 * rxmax) + fminf(bb1 * rymin, bb1 * rymax);
        float w2m = k2 + fminf(a2 * rxmin, a2 * rxmax) + fminf(bb2 * rymin, bb2 * rymax);
        return (w0m <= MARG) && (w1m <= MARG) && (w2m <= MARG);
    }
}

// ---------------- Kernel F: tile-major cull + bin (packed zlo|fid) ----------
__launch_bounds__(256)
__global__ void k_bincull(const float4* __restrict__ fd, int F,
                          int* __restrict__ cnt, unsigned* __restrict__ bins,
                          unsigned long long* __restrict__ zb) {
#pragma clang fp contract(off)
    __shared__ int scnt[4];
    __shared__ int sbase;
    int t = threadIdx.x;
    int lane = t & 63, wid = t >> 6;
    int tile = blockIdx.x >> 2;
    int q = blockIdx.x & 3;
    int tileX = tile & 15, tileY = tile >> 4;
    float txmin, txmax, tymin, tymax;
    tile_bounds(tileX, tileY, txmin, txmax, tymin, tymax);
    int Fq = (F + 3) >> 2;
    int fbeg = q * Fq;
    int fend = min(F, fbeg + Fq);
    int binbase = tile * CAP;

    for (int base = fbeg; base < fend; base += 256) {
        int f = base + t;
        bool pass = false;
        unsigned entry = 0;
        float x0, y0, x1, y1, x2, y2, area;
        float4 Bv;
        if (f < fend) {
            float4 A = fd[f * 3 + 0];
            Bv = fd[f * 3 + 1];
            area = Bv.z;
            if (fabsf(area) > EPSF) {
                x0 = A.x; y0 = A.y; x1 = A.z; y1 = A.w; x2 = Bv.x; y2 = Bv.y;
                pass = rect_cull(x0, y0, x1, y1, x2, y2, area,
                                 txmin, txmax, tymin, tymax);
                if (pass) {
                    // per-(tile,face) conservative depth lower bound:
                    // invz affine in (P,Q) -> max at tile corner; zlo = 1/max
                    float4 Cv = fd[f * 3 + 2];
                    float r0 = 1.0f / (area * Cv.x);
                    float r1 = 1.0f / (area * Cv.y);
                    float r2 = 1.0f / (area * Cv.z);
                    float a0 = y1 - y2, bb0 = x2 - x1, k0 = x1 * y2 - x2 * y1;
                    float a1 = y2 - y0, bb1 = x0 - x2, k1 = x2 * y0 - x0 * y2;
                    float a2 = y0 - y1, bb2 = x1 - x0, k2 = x0 * y1 - x1 * y0;
                    float K = (k0 * r0 + k1 * r1) + k2 * r2;
                    float GX = (a0 * r0 + a1 * r1) + a2 * r2;
                    float GY = (bb0 * r0 + bb1 * r1) + bb2 * r2;
                    float gx = fmaxf(GX * txmin, GX * txmax);
                    float gy = fmaxf(GY * tymin, GY * tymax);
                    float invmax = K + gx + gy;
                    float mag = (fabsf(k0 * r0) + fabsf(k1 * r1) + fabsf(k2 * r2))
                              + fmaxf(fabsf(GX * txmin), fabsf(GX * txmax))
                              + fmaxf(fabsf(GY * tymin), fabsf(GY * tymax));
                    invmax = invmax + 1e-5f * mag;
                    float zlo = (1.0f / fmaxf(invmax, EPSF)) * (1.0f - 1e-5f);
                    float qf = zlo * (1.0f / QSTEP);
                    int qz = (int)qf;             // floor for qf>=0
                    if (qf < 0.0f) qz = 0;
                    if (qz > 262143) qz = 262143;
                    entry = ((unsigned)qz << 14) | (unsigned)f;
                }
            }
        }
        unsigned long long m = __ballot(pass);
        if (lane == 0) scnt[wid] = __popcll(m);
        __syncthreads();
        int off = 0;
#pragma unroll
        for (int w = 0; w < 4; ++w)
            if (w < wid) off += scnt[w];
        int total = scnt[0] + scnt[1] + scnt[2] + scnt[3];
        if (t == 0) sbase = (total > 0) ? atomicAdd(&cnt[tile], total) : 0;
        __syncthreads();
        int sb = sbase;
        if (pass) {
            int rank = __popcll(m & ((1ull << lane) - 1ull));
            int s = sb + off + rank;
            if (s < CAP) {
                bins[binbase + s] = entry;
            } else {
                // overflow safety net (normally dead): rasterize directly
                float4 c = fd[f * 3 + 2];
                for (int p = 0; p < 256; ++p) {
                    int colp = tileX * 16 + (p & 15), rowp = tileY * 16 + (p >> 4);
                    float P = 1.0f - 2.0f * ((float)colp + 0.5f) / (float)IMGSZ;
                    float Q = 1.0f - 2.0f * ((float)rowp + 0.5f) / (float)IMGSZ;
                    float e0x = x0 - P, e0y = y0 - Q;
                    float e1x = x1 - P, e1y = y1 - Q;
                    float e2x = x2 - P, e2y = y2 - Q;
                    float w0 = e1x * e2y - e2x * e1y;
                    float w1 = e2x * e0y - e0x * e2y;
                    float w2 = (area - w0) - w1;
                    bool inside = (area > 0.0f) ? (w0 >= 0.0f && w1 >= 0.0f && w2 >= 0.0f)
                                                : (w0 <= 0.0f && w1 <= 0.0f && w2 <= 0.0f);
                    if (inside) {
                        float b0v = w0 / area, b1v = w1 / area, b2v = w2 / area;
                        float t0 = b0v / c.x, t1 = b1v / c.y, t2v = b2v / c.z;
                        float invz = (t0 + t1) + t2v;
                        float zpix = 1.0f / fmaxf(invz, EPSF);
                        unsigned long long pk =
                            ((unsigned long long)(unsigned int)__float_as_int(zpix) << 32) |
                            (unsigned int)__float_as_int(Bv.w);
                        atomicMin(&zb[rowp * IMGSZ + colp], pk);
                    }
                }
            }
        }
        __syncthreads();
    }
}

// ---------------- Kernel S: per-tile counting sort + fused work-list --------
__launch_bounds__(256)
__global__ void k_binsort(const int* __restrict__ cnt,
                          unsigned* __restrict__ bins,
                          unsigned short* __restrict__ workl,
                          int* __restrict__ worktotal) {
    __shared__ unsigned sent[CAP];       // 32 KB
    __shared__ int hist[64], hbase[64];
    __shared__ int sn[256], snseg[256], sord[256], spre[256];
    int t = threadIdx.x;
    if (blockIdx.x == 256) {
        int n = cnt[t];
        if (n > CAP) n = CAP;
        int ns = (n > 0) ? (n + SEGLEN - 1) / SEGLEN : 0;
        sn[t] = n;
        snseg[t] = ns;
        __syncthreads();
        int r = 0;
        for (int k = 0; k < 256; ++k) {
            int nk = sn[k];
            r += (nk > n) || (nk == n && k < t);
        }
        sord[r] = t;
        __syncthreads();
        if (t == 0) {
            int run = 0;
            for (int k = 0; k < 256; ++k) { spre[k] = run; run += snseg[sord[k]]; }
            *worktotal = run;
        }
        __syncthreads();
        int tile = sord[t];
        int base = spre[t];
        int ns2 = snseg[tile];
        for (int seg = 0; seg < ns2; ++seg)
            workl[base + seg] = (unsigned short)((tile << 6) | seg);
        return;
    }
    int tile = blockIdx.x;
    int n = cnt[tile];
    if (n > CAP) n = CAP;
    if (n == 0) return;
    int nseg = (n + SEGLEN - 1) / SEGLEN;
    if (t < 64) hist[t] = 0;
    __syncthreads();
    for (int i = t; i < n; i += 256) {
        unsigned e = bins[tile * CAP + i];
        sent[i] = e;
        atomicAdd(&hist[e >> 26], 1);
    }
    __syncthreads();
    if (t == 0) {
        int run = 0;
        for (int k = 0; k < 64; ++k) { hbase[k] = run; run += hist[k]; }
    }
    __syncthreads();
    if (t < 64) hist[t] = 0;   // reuse as per-bucket fill counter
    __syncthreads();
    for (int i = t; i < n; i += 256) {
        unsigned e = sent[i];
        int b = e >> 26;
        int pos = hbase[b] + atomicAdd(&hist[b], 1);
        int tpos = (pos % nseg) * SEGLEN + pos / nseg;
        bins[tile * CAP + tpos] = e;
    }
}

// ---------------- Kernel D: (tile,seg) blocks; shared staging; subtile waves
__launch_bounds__(256)
__global__ void k_rastseg(const float4* __restrict__ fd,
                          const int* __restrict__ cnt,
                          const unsigned* __restrict__ bins,
                          const unsigned short* __restrict__ workl,
                          const int* __restrict__ worktotal,
                          unsigned long long* __restrict__ zb) {
#pragma clang fp contract(off)
    __shared__ float4 sA[64], sB[64], sC[64];
    __shared__ unsigned sE[64];
    __shared__ int sdone[4];
    int total = *worktotal;
    int wave = threadIdx.x >> 6;
    int lane = threadIdx.x & 63;
    int t = threadIdx.x;
    for (int wi = blockIdx.x; wi < total; wi += gridDim.x) {
        int w = workl[wi];
        int tile = w >> 6, seg = w & 63;
        int n = cnt[tile];
        if (n > CAP) n = CAP;
        int nseg = (n + SEGLEN - 1) / SEGLEN;
        int nb = (n - 1 - seg) / nseg + 1;   // subsequence length (<= SEGLEN)
        int binbase = tile * CAP + seg * SEGLEN;

        int tileX = tile & 15, tileY = tile >> 4;
        int col0 = tileX * 16 + ((wave & 1) << 3);
        int row0 = tileY * 16 + ((wave >> 1) << 3);
        int col = col0 + (lane & 7);
        int row = row0 + (lane >> 3);
        int pix = row * IMGSZ + col;
        float P = 1.0f - 2.0f * ((float)col + 0.5f) / (float)IMGSZ;
        float Q = 1.0f - 2.0f * ((float)row + 0.5f) / (float)IMGSZ;
        float sxmax = 1.0f - 2.0f * ((float)col0 + 0.5f) / (float)IMGSZ;
        float sxmin = 1.0f - 2.0f * ((float)(col0 + 7) + 0.5f) / (float)IMGSZ;
        float symax = 1.0f - 2.0f * ((float)row0 + 0.5f) / (float)IMGSZ;
        float symin = 1.0f - 2.0f * ((float)(row0 + 7) + 0.5f) / (float)IMGSZ;

        unsigned long long seed = zb[pix];
        unsigned long long bestpk = seed;
        float bestz = decode_bestz(seed);
        bool done = false;
        if (lane == 0) sdone[wave] = 0;

        for (int k0 = 0; k0 < nb; k0 += 64) {
            int cnum = min(64, nb - k0);
            __syncthreads();  // LDS reuse + sdone visibility
            if (sdone[0] + sdone[1] + sdone[2] + sdone[3] == 4) break;
            if (t < 192) {
                int part = t >> 6, fi = t & 63;
                if (fi < cnum) {
                    unsigned e = bins[binbase + k0 + fi];
                    int fid = e & 0x3FFF;
                    if (part == 0) { sE[fi] = e; sA[fi] = fd[fid * 3 + 0]; }
                    else if (part == 1) sB[fi] = fd[fid * 3 + 1];
                    else sC[fi] = fd[fid * 3 + 2];
                }
            }
            __syncthreads();
            if (!done) {
                bool pass8 = false;
                if (lane < cnum) {
                    float4 ra = sA[lane], rb = sB[lane];
                    float area = rb.z;
                    if (fabsf(area) > EPSF)
                        pass8 = rect_cull(ra.x, ra.y, ra.z, ra.w, rb.x, rb.y,
                                          area, sxmin, sxmax, symin, symax);
                }
                unsigned long long mm = __ballot(pass8);
                int it = 0;
                while (mm) {
                    int s = __ffsll(mm) - 1;
                    mm &= mm - 1;
                    unsigned e = sE[s];
                    float zlo = (float)(e >> 14) * QSTEP;
                    if ((it++ & 7) == 0) {
                        // subsequence ascending in bucket(e>>26): remaining
                        // faces' zpix >= bucket-lo; if > all bestz, every
                        // remaining pk is strictly worse. Bit-exact.
                        float blo = (float)(e >> 26) * (4096.0f * QSTEP);
                        if (__all(blo > bestz)) {
                            done = true;
                            if (lane == 0) sdone[wave] = 1;
                            break;
                        }
                    }
                    if (zlo > bestz) {
                        if (__all(zlo > bestz)) continue;
                    }
                    float4 a = sA[s], b = sB[s];
                    float area = b.z;
                    float e0x = a.x - P, e0y = a.y - Q;
                    float e1x = a.z - P, e1y = a.w - Q;
                    float e2x = b.x - P, e2y = b.y - Q;
                    float w0 = e1x * e2y - e2x * e1y;
                    float w1 = e2x * e0y - e0x * e2y;
                    float w2 = (area - w0) - w1;
                    bool inside = (area > 0.0f) ? (w0 >= 0.0f && w1 >= 0.0f && w2 >= 0.0f)
                                                : (w0 <= 0.0f && w1 <= 0.0f && w2 <= 0.0f);
                    bool want = inside && !(zlo > bestz);
                    if (want) {
                        float4 cc = sC[s];
                        float b0v = w0 / area, b1v = w1 / area, b2v = w2 / area;
                        float t0 = b0v / cc.x, t1 = b1v / cc.y, t2v = b2v / cc.z;
                        float invz = (t0 + t1) + t2v;
                        float zpix = 1.0f / fmaxf(invz, EPSF);
                        unsigned long long pk =
                            ((unsigned long long)(unsigned int)__float_as_int(zpix) << 32) |
                            (unsigned int)__float_as_int(b.w);
                        if (pk < bestpk) {
                            bestpk = pk;
                            bestz = zpix;
                        }
                    }
                }
            }
        }
        if (bestpk < seed) atomicMin(&zb[pix], bestpk);
        __syncthreads();  // all waves finished with this item's LDS
    }
}

// ---------------- Kernel D-mono: fallback (small ws_size) -------------------
__launch_bounds__(256)
__global__ void k_raster_mono(const float4* __restrict__ fd, int F,
                              unsigned long long* __restrict__ zb) {
#pragma clang fp contract(off)
    __shared__ float4 sfd[256 * 3];
    __shared__ int scnt[4];
    int t = threadIdx.x;
    int lane = t & 63, wid = t >> 6;
    int tile = blockIdx.x & 255;
    int slice = blockIdx.x >> 8;
    int tileX = tile & 15, tileY = tile >> 4;
    int col = tileX * 16 + (t & 15);
    int row = tileY * 16 + (t >> 4);
    int pix = row * IMGSZ + col;
    float P = 1.0f - 2.0f * ((float)col + 0.5f) / (float)IMGSZ;
    float Q = 1.0f - 2.0f * ((float)row + 0.5f) / (float)IMGSZ;
    float txmin, txmax, tymin, tymax;
    tile_bounds(tileX, tileY, txmin, txmax, tymin, tymax);
    int fbeg = slice * SLICE_LEN;
    int fend = fbeg + SLICE_LEN;
    if (fend > F) fend = F;
    unsigned long long bestpk = SENTINEL;
    float bestz = BIGF;
    for (int base = fbeg; base < fend; base += 256) {
        unsigned long long ext = zb[pix];
        if (ext < bestpk) {
            bestpk = ext;
            bestz = decode_bestz(ext);
        }
        int f = base + t;
        bool pass = false;
        float4 A, B, C;
        if (f < fend) {
            A = fd[f * 3 + 0];
            B = fd[f * 3 + 1];
            C = fd[f * 3 + 2];
            float area = B.z;
            if (fabsf(area) > EPSF)
                pass = rect_cull(A.x, A.y, A.z, A.w, B.x, B.y, area,
                                 txmin, txmax, tymin, tymax);
        }
        unsigned long long m = __ballot(pass);
        if (lane == 0) scnt[wid] = __popcll(m);
        __syncthreads();
        int off = 0;
#pragma unroll
        for (int w = 0; w < 4; ++w)
            if (w < wid) off += scnt[w];
        int total = scnt[0] + scnt[1] + scnt[2] + scnt[3];
        if (pass) {
            int rank = __popcll(m & ((1ull << lane) - 1ull));
            int s = off + rank;
            sfd[s * 3 + 0] = A;
            sfd[s * 3 + 1] = B;
            sfd[s * 3 + 2] = C;
        }
        __syncthreads();
        for (int s = 0; s < total; ++s) {
            float4 a = sfd[s * 3 + 0], b = sfd[s * 3 + 1], c = sfd[s * 3 + 2];
            float e0x = a.x - P, e0y = a.y - Q;
            float e1x = a.z - P, e1y = a.w - Q;
            float e2x = b.x - P, e2y = b.y - Q;
            float w0 = e1x * e2y - e2x * e1y;
            float w1 = e2x * e0y - e0x * e2y;
            float area = b.z;
            float w2 = (area - w0) - w1;
            bool inside = (area > 0.0f) ? (w0 >= 0.0f && w1 >= 0.0f && w2 >= 0.0f)
                                        : (w0 <= 0.0f && w1 <= 0.0f && w2 <= 0.0f);
            bool want = inside && !(c.w > bestz);  // equality-safe (zminb)
            if (want) {
                float b0v = w0 / area, b1v = w1 / area, b2v = w2 / area;
                float t0 = b0v / c.x, t1 = b1v / c.y, t2v = b2v / c.z;
                float invz = (t0 + t1) + t2v;
                float zpix = 1.0f / fmaxf(invz, EPSF);
                unsigned long long pk =
                    ((unsigned long long)(unsigned int)__float_as_int(zpix) << 32) |
                    (unsigned int)__float_as_int(b.w);
                if (pk < bestpk) {
                    bestpk = pk;
                    bestz = zpix;
                }
            }
        }
        if (bestpk < ext) atomicMin(&zb[pix], bestpk);
        __syncthreads();
    }
}

// ---------------- Kernel E: shade winners (inline normal normalize) ---------
__launch_bounds__(256)
__global__ void k_shade(const unsigned long long* __restrict__ zb,
                        const float4* __restrict__ fd,
                        const int* __restrict__ faces,
                        const float* __restrict__ verts,
                        const float* __restrict__ vn,
                        const float* __restrict__ tm,
                        float* __restrict__ out) {
#pragma clang fp contract(off)
    int pix = blockIdx.x * 256 + threadIdx.x;
    unsigned long long pk = zb[pix];
    float val = 0.0f, alpha = 0.0f;
    if (pk != SENTINEL) {
        float depth = __uint_as_float((unsigned int)(pk >> 32));
        if (depth < 0.5f * BIGF) {
            int bestf = (int)(unsigned int)(pk & 0xFFFFFFFFull);
            int col = pix & (IMGSZ - 1), row = pix >> 8;
            float P = 1.0f - 2.0f * ((float)col + 0.5f) / (float)IMGSZ;
            float Q = 1.0f - 2.0f * ((float)row + 0.5f) / (float)IMGSZ;
            float4 a = fd[bestf * 3 + 0], b = fd[bestf * 3 + 1], c = fd[bestf * 3 + 2];
            float e0x = a.x - P, e0y = a.y - Q;
            float e1x = a.z - P, e1y = a.w - Q;
            float e2x = b.x - P, e2y = b.y - Q;
            float w0 = e1x * e2y - e2x * e1y;
            float w1 = e2x * e0y - e0x * e2y;
            float area = b.z;
            float t0 = (w0 / area) / c.x, t1 = (w1 / area) / c.y;
            float t2v = (((area - w0) - w1) / area) / c.z;
            float invz = (t0 + t1) + t2v;
            float zpix = 1.0f / fmaxf(invz, EPSF);
            float bp0 = t0 * zpix, bp1 = t1 * zpix;

            int i0 = faces[bestf * 3 + 0], i1 = faces[bestf * 3 + 1], i2 = faces[bestf * 3 + 2];
            float b0v = bp0, b1v = bp1, b2v = (1.0f - bp0) - bp1;
            float Pwx = (b0v * verts[i0 * 3 + 0] + b1v * verts[i1 * 3 + 0]) + b2v * verts[i2 * 3 + 0];
            float Pwy = (b0v * verts[i0 * 3 + 1] + b1v * verts[i1 * 3 + 1]) + b2v * verts[i2 * 3 + 1];
            float Pwz = (b0v * verts[i0 * 3 + 2] + b1v * verts[i1 * 3 + 2]) + b2v * verts[i2 * 3 + 2];
            float v0x = vn[i0 * 3 + 0], v0y = vn[i0 * 3 + 1], v0z = vn[i0 * 3 + 2];
            float n0 = sqrtf((v0x * v0x + v0y * v0y) + v0z * v0z) + EPSF;
            v0x /= n0; v0y /= n0; v0z /= n0;
            float v1x = vn[i1 * 3 + 0], v1y = vn[i1 * 3 + 1], v1z = vn[i1 * 3 + 2];
            float n1 = sqrtf((v1x * v1x + v1y * v1y) + v1z * v1z) + EPSF;
            v1x /= n1; v1y /= n1; v1z /= n1;
            float v2x = vn[i2 * 3 + 0], v2y = vn[i2 * 3 + 1], v2z = vn[i2 * 3 + 2];
            float n2 = sqrtf((v2x * v2x + v2y * v2y) + v2z * v2z) + EPSF;
            v2x /= n2; v2y /= n2; v2z /= n2;
            float Nx = (b0v * v0x + b1v * v1x) + b2v * v2x;
            float Ny = (b0v * v0y + b1v * v1y) + b2v * v2y;
            float Nz = (b0v * v0z + b1v * v1z) + b2v * v2z;
            float nn = sqrtf((Nx * Nx + Ny * Ny) + Nz * Nz) + EPSF;
            Nx /= nn; Ny /= nn; Nz /= nn;
            float T0 = tm[3], T1 = tm[7], T2 = tm[11];
            float camx = -((T0 * tm[0] + T1 * tm[1]) + T2 * tm[2]);
            float camy = -((T0 * tm[4] + T1 * tm[5]) + T2 * tm[6]);
            float camz = -((T0 * tm[8] + T1 * tm[9]) + T2 * tm[10]);
            float Ldx = 0.0f - Pwx, Ldy = 0.0f - Pwy, Ldz = 3.0f - Pwz;
            float ln = sqrtf((Ldx * Ldx + Ldy * Ldy) + Ldz * Ldz) + EPSF;
            Ldx /= ln; Ldy /= ln; Ldz /= ln;
            float Vx = camx - Pwx, Vy = camy - Pwy, Vz = camz - Pwz;
            float vv = sqrtf((Vx * Vx + Vy * Vy) + Vz * Vz) + EPSF;
            Vx /= vv; Vy /= vv; Vz /= vv;
            float dt = (Nx * Ldx + Ny * Ldy) + Nz * Ldz;
            float ndl = fmaxf(dt, 0.0f);
            float twodt = 2.0f * dt;
            float rx = -Ldx + twodt * Nx;
            float ry = -Ldy + twodt * Ny;
            float rz = -Ldz + twodt * Nz;
            float sdot = (rx * Vx + ry * Vy) + rz * Vz;
            float sb = fmaxf(sdot, 0.0f);
            float s2 = sb * sb, s4 = s2 * s2, s8 = s4 * s4, s16 = s8 * s8, s32 = s16 * s16;
            float spec = s32 * s32;  // sb^64
            float shade = (0.5f + 0.3f * ndl) + 0.2f * spec;
            val = shade * 255.0f;
            alpha = 1.0f;
        }
    }
    out[0 * HW + pix] = val;
    out[1 * HW + pix] = val;
    out[2 * HW + pix] = val;
    out[3 * HW + pix] = alpha;
}

// ---------------- launcher --------------------------------------------------
extern "C" void kernel_launch(void* const* d_in, const int* in_sizes, int n_in,
                              void* d_out, int out_size, void* d_ws, size_t ws_size,
                              hipStream_t stream) {
    const float* verts = (const float*)d_in[0];
    const float* tm = (const float*)d_in[1];
    const float* focal = (const float*)d_in[2];
    const int* faces = (const int*)d_in[3];
    int V = in_sizes[0] / 3;  // B=1
    int F = in_sizes[3] / 3;

    char* base = (char*)d_ws;
    unsigned long long* zb = (unsigned long long*)base;            // HW*8
    int* cnt = (int*)(base + (size_t)HW * 8);                      // 4KB
    float* vn = (float*)(base + (size_t)HW * 8 + 4096);            // 3V floats
    size_t fdByte = ((size_t)HW * 8 + 4096 + 3 * (size_t)V * 4 + 15) & ~(size_t)15;
    float4* fd = (float4*)(base + fdByte);
    size_t binByte = fdByte + (size_t)F * 48;
    unsigned* bins = (unsigned*)(base + binByte);
    size_t workByte = binByte + (size_t)256 * CAP * 4;
    unsigned short* workl = (unsigned short*)(base + workByte);    // <=16384 u16
    int* worktotal = (int*)(base + workByte + 16384 * 2);
    size_t needBinned = workByte + 16384 * 2 + 64;
    float* out = (float*)d_out;

    int fb = (F + 255) / 256;
    k_init<<<128, 256, 0, stream>>>(zb, cnt, vn, V);
    k_facesetup<<<fb, 256, 0, stream>>>(faces, verts, tm, focal, fd, vn, F);
    if (ws_size >= needBinned) {
        k_bincull<<<256 * 4, 256, 0, stream>>>(fd, F, cnt, bins, zb);
        k_binsort<<<257, 256, 0, stream>>>(cnt, bins, workl, worktotal);
        k_rastseg<<<RBLOCKS, 256, 0, stream>>>(fd, cnt, bins, workl, worktotal, zb);
    } else {
        int nslice = (F + SLICE_LEN - 1) / SLICE_LEN;
        k_raster_mono<<<256 * nslice, 256, 0, stream>>>(fd, F, zb);
    }
    k_shade<<<HW / 256, 256, 0, stream>>>(zb, fd, faces, verts, vn, tm, out);
}